// Round 4
// baseline (3610.321 us; speedup 1.0000x reference)
//
#include <hip/hip_runtime.h>

// ---------------- constants ----------------
#define T_ENC 64
#define T_DEC 99

// bf16 weight workspace (elements), fragment-permuted, uniform 6 slots/layer:
// phase blob = 4 layers x 6 slots; slot s: 0..2 = h-side gates r/z/n, 3..5 = x-side
// gates r/z/n (layer 0 x-side = wih0 zero-padded to K=128 -> only ks=0/quad=0 nonzero).
// slot[w][ks][lane][e] (8*4*64*8=16384 els): element = W[g*128 + w*16 + ln][ks*32 + quad*8 + e]
#define SLOT    16384
#define PH_BLOB 393216          // 24 slots
#define O_LIN1  786432          // 1 slot (lin1 B-frags)
#define W_TOTAL 802816

// output layout (f32 elements)
#define DEC_OUT_OFF 0
#define DEC_HID_OFF 1638400
#define ENC_OUT_OFF 3735552
#define ENC_HID_OFF 37289984
#define LOSS_OFF    39387136

typedef short short8_t __attribute__((ext_vector_type(8)));
typedef float f32x4 __attribute__((ext_vector_type(4)));

#define MFMA16(a, b, c) __builtin_amdgcn_mfma_f32_16x16x32_bf16((a), (b), (c), 0, 0, 0)

__device__ __forceinline__ unsigned short f2bf(float f) {
  unsigned u = __builtin_bit_cast(unsigned, f);
  u = (u + 0x7FFFu + ((u >> 16) & 1u)) >> 16;
  return (unsigned short)u;
}
__device__ __forceinline__ float sigm(float x) {
  return __builtin_amdgcn_rcpf(1.f + __expf(-x));
}
__device__ __forceinline__ float tanh_fast(float x) {
  x = fminf(fmaxf(x, -15.f), 15.f);
  float e = __expf(-2.f * x);
  return (1.f - e) * __builtin_amdgcn_rcpf(1.f + e);
}

// ---------------- weight fp32 -> bf16 fragment-permute ----------------
__global__ void convert_weights(const float* __restrict__ ewih0, const float* __restrict__ ewhh0,
                                const float* __restrict__ ewih, const float* __restrict__ ewhh,
                                const float* __restrict__ dwih0, const float* __restrict__ dwhh0,
                                const float* __restrict__ dwih, const float* __restrict__ dwhh,
                                const float* __restrict__ lin1w, unsigned short* __restrict__ wb) {
  int i = blockIdx.x * 256 + threadIdx.x;
  if (i >= W_TOTAL) return;
  float v;
  if (i < O_LIN1) {
    const int ph = i / PH_BLOB;
    const int li = i % PH_BLOB;
    const float* wih0 = ph ? dwih0 : ewih0;
    const float* whh0 = ph ? dwhh0 : ewhh0;
    const float* wih  = ph ? dwih  : ewih;
    const float* whh  = ph ? dwhh  : ewhh;
    const int l = li / (6 * SLOT);
    const int r6 = li % (6 * SLOT);
    const int s = r6 / SLOT, r = r6 % SLOT;
    const int w = r >> 11, ks = (r >> 9) & 3, lane = (r >> 3) & 63, e = r & 7;
    const int quad = lane >> 4, ln = lane & 15;
    const int g = (s < 3) ? s : (s - 3);
    const int row = g * 128 + w * 16 + ln;
    const int col = ks * 32 + quad * 8 + e;
    if (s < 3) {  // h-side
      v = (l == 0) ? whh0[row * 128 + col] : whh[(l - 1) * 49152 + row * 128 + col];
    } else {      // x-side (layer 0: wih0 is [384][4], zero-padded beyond col 3)
      v = (l == 0) ? (col < 4 ? wih0[row * 4 + col] : 0.f)
                   : wih[(l - 1) * 49152 + row * 128 + col];
    }
  } else {
    const int r = i - O_LIN1;
    const int w = r >> 11, ks = (r >> 9) & 3, lane = (r >> 3) & 63, e = r & 7;
    const int quad = lane >> 4, ln = lane & 15;
    v = lin1w[(w * 16 + ln) * 128 + ks * 32 + quad * 8 + e];
  }
  wb[i] = f2bf(v);
}

__global__ void zero_loss_k(float* out) { out[LOSS_OFF] = 0.f; }

// ---------------- main persistent kernel ----------------
// grid = 256 blocks (M=16 batch rows, 1 block/CU), block = 512 threads (8 waves).
// KEY (R3 fix): grid==CU-count means launch_bounds(512,2) only capped VGPRs (256).
// With (512,1) the 512-VGPR budget lets the ENTIRE per-phase weight set live in
// registers per wave (364 VGPRs of fragments, loaded once per phase) -> the
// 192 KiB/CU/layer-step L2 weight stream (R3's ~3500-cycle floor) disappears.
// l-loop fully unrolled (constant indices -> registers); t-loop unroll(1).
// L0 x-side uses only ks=0 frags (wih0 zero-padded: nonzero only ks=0/quad=0).
// fp32 h master in LDS (hf); bf16 h in swizzled LDS (hb) for MFMA A-frags.
__global__ __launch_bounds__(512, 1) void gru_seq2seq(
    const float* __restrict__ inp, const float* __restrict__ tgt,
    const float* __restrict__ enc_bih, const float* __restrict__ enc_bhh,
    const float* __restrict__ dec_bih, const float* __restrict__ dec_bhh,
    const float* __restrict__ lin1_b, const float* __restrict__ lin2_w,
    const float* __restrict__ lin2_b, const unsigned short* __restrict__ wb,
    float* __restrict__ out) {
  const int tid = threadIdx.x;
  const int wave = tid >> 6;
  const int lane = tid & 63;
  const int ln = lane & 15;
  const int quad = lane >> 4;
  const int b0 = blockIdx.x * 16;
  const int j = (wave << 4) + ln;

  __shared__ unsigned short hb[2][4][16][128];  // bf16 h, [parity][layer][m][swz k]
  __shared__ unsigned short xt[2][16][128];     // bf16 x-tile, zero-padded K=128
  __shared__ float hf[4][16][128];              // fp32 h master
  __shared__ float biasi[4][384];
  __shared__ float biash[4][384];
  __shared__ float lin1bs[128];
  __shared__ float lin2ws[4][129];
  __shared__ float lin2bs[4];
  __shared__ float relu_s[16][129];

  for (int i = tid; i < 2 * 4 * 16 * 128; i += 512) ((unsigned short*)hb)[i] = 0;
  for (int i = tid; i < 2 * 16 * 128; i += 512) ((unsigned short*)xt)[i] = 0;
  for (int i = tid; i < 4 * 16 * 128; i += 512) ((float*)hf)[i] = 0.f;
  if (tid < 128) lin1bs[tid] = lin1_b[tid];
  { int e = tid >> 7, k = tid & 127; lin2ws[e][k] = lin2_w[e * 128 + k]; }
  if (tid < 4) lin2bs[tid] = lin2_b[tid];

  float loss_local = 0.f;

  // decoder_output[:, 0, :] = inp[:, 0, :]
  if (tid < 64) {
    int m = tid >> 2, e = tid & 3;
    out[DEC_OUT_OFF + (b0 + m) * 400 + e] = inp[(b0 + m) * 256 + e];
  }

  const int fofs = wave * 2048 + lane * 8;  // [w][ks][lane][8] within a slot

  // lin1 B-frags: register-resident for the whole kernel (16 VGPRs)
  short8_t w1f[4];
#pragma unroll
  for (int ks = 0; ks < 4; ks++)
    w1f[ks] = *(const short8_t*)(wb + O_LIN1 + fofs + ks * 512);

#pragma unroll 1
  for (int ph = 0; ph < 2; ph++) {
    const float* bih = ph ? dec_bih : enc_bih;
    const float* bhh = ph ? dec_bhh : enc_bhh;
    for (int i = tid; i < 1536; i += 512) {
      ((float*)biasi)[i] = bih[i];
      ((float*)biash)[i] = bhh[i];
    }
    // step-0 input for both phases: inp[:, 0, :]
    if (tid < 64) {
      int m = tid >> 2, e = tid & 3;
      xt[0][m][(m << 3) | e] = f2bf(inp[(b0 + m) * 256 + e]);
    }
    __syncthreads();

    // ---- per-phase register-resident weights (l fully unrolled -> constant idx) ----
    const unsigned short* PB = wb + ph * PH_BLOB + fofs;
    short8_t wh[4][3][4];   // h-side  [l][gate][ks]
    short8_t wx[3][3][4];   // x-side  [l-1][gate][ks], layers 1..3
    short8_t wx0[3];        // x-side layer 0, ks=0 only
#pragma unroll
    for (int l = 0; l < 4; l++) {
      const unsigned short* LB = PB + l * (6 * SLOT);
#pragma unroll
      for (int g = 0; g < 3; g++) {
#pragma unroll
        for (int ks = 0; ks < 4; ks++)
          wh[l][g][ks] = *(const short8_t*)(LB + g * SLOT + ks * 512);
        if (l == 0) {
          wx0[g] = *(const short8_t*)(LB + (3 + g) * SLOT);
        } else {
#pragma unroll
          for (int ks = 0; ks < 4; ks++)
            wx[l - 1][g][ks] = *(const short8_t*)(LB + (3 + g) * SLOT + ks * 512);
        }
      }
    }
    // per-lane bias sums, hoisted out of the t-loop (16 VGPRs)
    float brg[4], bzg[4], bing[4], bhng[4];
#pragma unroll
    for (int l = 0; l < 4; l++) {
      brg[l] = biasi[l][j] + biash[l][j];
      bzg[l] = biasi[l][128 + j] + biash[l][128 + j];
      bing[l] = biasi[l][256 + j];
      bhng[l] = biash[l][256 + j];
    }
    const float l1b = lin1bs[j];

    const int T = ph ? T_DEC : T_ENC;

#pragma unroll 1
    for (int t = 0; t < T; t++) {
      const int p = t & 1;
#pragma unroll
      for (int l = 0; l < 4; l++) {
        f32x4 ar = {0.f, 0.f, 0.f, 0.f}, az = {0.f, 0.f, 0.f, 0.f};
        f32x4 ani = {0.f, 0.f, 0.f, 0.f}, anh = {0.f, 0.f, 0.f, 0.f};
        const unsigned short* ahb = &hb[1 - p][l][0][0] + ln * 128;
#pragma unroll
        for (int ks = 0; ks < 4; ks++) {
          const int pc = (((ks * 4 + quad) ^ ln) << 3);
          short8_t a_h = *(const short8_t*)(ahb + pc);
          ar = MFMA16(a_h, wh[l][0][ks], ar);
          az = MFMA16(a_h, wh[l][1][ks], az);
          anh = MFMA16(a_h, wh[l][2][ks], anh);
          if (l > 0) {
            short8_t a_x = *(const short8_t*)(&hb[p][l - 1][0][0] + ln * 128 + pc);
            ar = MFMA16(a_x, wx[l - 1][0][ks], ar);
            az = MFMA16(a_x, wx[l - 1][1][ks], az);
            ani = MFMA16(a_x, wx[l - 1][2][ks], ani);
          }
        }
        if (l == 0) {  // x-side of layer 0: only ks=0 is nonzero
          const int pc0 = ((quad ^ ln) << 3);
          short8_t a_x0 = *(const short8_t*)(&xt[p][0][0] + ln * 128 + pc0);
          ar = MFMA16(a_x0, wx0[0], ar);
          az = MFMA16(a_x0, wx0[1], az);
          ani = MFMA16(a_x0, wx0[2], ani);
        }
        // ---- epilogue ----
#pragma unroll
        for (int r = 0; r < 4; r++) {
          const int m = quad * 4 + r;
          const float hp = hf[l][m][j];
          const float rg = sigm(ar[r] + brg[l]);
          const float zg = sigm(az[r] + bzg[l]);
          const float ng = tanh_fast(ani[r] + bing[l] + rg * (anh[r] + bhng[l]));
          const float hn = (1.f - zg) * ng + zg * hp;
          hf[l][m][j] = hn;
          hb[p][l][m][(((j >> 3) ^ m) << 3) | (j & 7)] = f2bf(hn);
          if (!ph) {
            if (l == 3) out[ENC_OUT_OFF + ((b0 + m) * 64 + t) * 128 + j] = hn;
            if (t == T_ENC - 1) out[ENC_HID_OFF + (l * 4096 + b0 + m) * 128 + j] = hn;
          } else if (t == T_DEC - 1) {
            out[DEC_HID_OFF + (l * 4096 + b0 + m) * 128 + j] = hn;
          }
        }
        // prefetch next step's x before the barrier (readers come after it)
        if (l == 3 && (t + 1) < T && tid < 64) {
          int m = tid >> 2, e = tid & 3;
          float xv = ph ? tgt[(b0 + m) * 400 + (t + 1) * 4 + e]
                        : inp[(b0 + m) * 256 + (t + 1) * 4 + e];
          xt[1 - p][m][(m << 3) | e] = f2bf(xv);
        }
        __syncthreads();
      }  // layer

      if (ph) {
        // ---- lin1 (128x128) via MFMA, register-resident weights ----
        f32x4 a1 = {0.f, 0.f, 0.f, 0.f};
        const unsigned short* h3 = &hb[p][3][0][0] + ln * 128;
#pragma unroll
        for (int ks = 0; ks < 4; ks++) {
          const int pc = (((ks * 4 + quad) ^ ln) << 3);
          short8_t ah = *(const short8_t*)(h3 + pc);
          a1 = MFMA16(ah, w1f[ks], a1);
        }
#pragma unroll
        for (int r = 0; r < 4; r++) {
          const int m = quad * 4 + r;
          const float v = a1[r] + l1b;
          relu_s[m][j] = v > 0.f ? v : 0.f;
        }
        __syncthreads();
        // ---- lin2 (4x128) + loss, threads 0..63 ----
        if (tid < 64) {
          const int m = tid >> 2, e = tid & 3;
          float acc = lin2bs[e];
#pragma unroll 8
          for (int k = 0; k < 128; k++) acc += relu_s[m][k] * lin2ws[e][k];
          const int oidx = (b0 + m) * 400 + (t + 1) * 4 + e;
          out[DEC_OUT_OFF + oidx] = acc;
          const float d = acc - tgt[oidx];
          loss_local += d * d;
        }
      }
    }  // t
  }  // phase

  // ---- loss reduction: only wave 0 has nonzero partials ----
  loss_local *= (1.f / 16384.f);  // mean over (B=4096, E=4)
#pragma unroll
  for (int off = 32; off; off >>= 1) loss_local += __shfl_down(loss_local, off);
  if (tid == 0) atomicAdd(&out[LOSS_OFF], loss_local);
}

// ---------------- launch ----------------
extern "C" void kernel_launch(void* const* d_in, const int* in_sizes, int n_in,
                              void* d_out, int out_size, void* d_ws, size_t ws_size,
                              hipStream_t stream) {
  const float* inp      = (const float*)d_in[0];
  const float* tgt      = (const float*)d_in[1];
  const float* enc_wih0 = (const float*)d_in[2];
  const float* enc_whh0 = (const float*)d_in[3];
  const float* enc_wih  = (const float*)d_in[4];
  const float* enc_whh  = (const float*)d_in[5];
  const float* enc_bih  = (const float*)d_in[6];
  const float* enc_bhh  = (const float*)d_in[7];
  const float* dec_wih0 = (const float*)d_in[8];
  const float* dec_whh0 = (const float*)d_in[9];
  const float* dec_wih  = (const float*)d_in[10];
  const float* dec_whh  = (const float*)d_in[11];
  const float* dec_bih  = (const float*)d_in[12];
  const float* dec_bhh  = (const float*)d_in[13];
  const float* lin1_w   = (const float*)d_in[14];
  const float* lin1_b   = (const float*)d_in[15];
  const float* lin2_w   = (const float*)d_in[16];
  const float* lin2_b   = (const float*)d_in[17];
  unsigned short* wb = (unsigned short*)d_ws;
  float* out = (float*)d_out;

  hipLaunchKernelGGL(convert_weights, dim3((W_TOTAL + 255) / 256), dim3(256), 0, stream,
                     enc_wih0, enc_whh0, enc_wih, enc_whh, dec_wih0, dec_whh0, dec_wih,
                     dec_whh, lin1_w, wb);
  hipLaunchKernelGGL(zero_loss_k, dim3(1), dim3(1), 0, stream, out);
  hipLaunchKernelGGL(gru_seq2seq, dim3(256), dim3(512), 0, stream,
                     inp, tgt, enc_bih, enc_bhh, dec_bih, dec_bhh,
                     lin1_b, lin2_w, lin2_b, wb, out);
}

// Round 5
// 1131.234 us; speedup vs baseline: 3.1915x; 3.1915x over previous
//
#include <hip/hip_runtime.h>

// ---------------- constants ----------------
#define T_ENC 64
#define T_DEC 99

// fp8 e4m3 weight workspace (BYTES), fragment-permuted, uniform 6 slots/layer:
// phase blob = 4 layers x 6 slots; slot s: 0..2 = h-side gates r/z/n, 3..5 = x-side
// gates r/z/n (layer 0 x-side = wih0 zero-padded to K=128 -> only ks=0 nonzero).
// slot[w][ks][lane][e] (8*4*64*8 = 16384 BYTES): byte e of lane (quad,ln) =
//   W[g*128 + w*16 + ln][ks*32 + quad*8 + e]   (fp8 16x16x32 B-layout, 8 B/lane)
#define SLOT    16384
#define PH_BLOB 393216          // 24 slots
#define O_LIN1  786432          // 1 slot (lin1 B-frags)
#define W_TOTAL 802816

// output layout (f32 elements)
#define DEC_OUT_OFF 0
#define DEC_HID_OFF 1638400
#define ENC_OUT_OFF 3735552
#define ENC_HID_OFF 37289984
#define LOSS_OFF    39387136

typedef float f32x4 __attribute__((ext_vector_type(4)));

#define MFMA8(a, b, c) __builtin_amdgcn_mfma_f32_16x16x32_fp8_fp8((a), (b), (c), 0, 0, 0)

__device__ __forceinline__ unsigned f2fp8pk(float a, float b) {
  // D[7:0] = e4m3(a), D[15:8] = e4m3(b)  (OCP on gfx950)
  return (unsigned)__builtin_amdgcn_cvt_pk_fp8_f32(a, b, 0, false);
}
__device__ __forceinline__ float sigm(float x) {
  return __builtin_amdgcn_rcpf(1.f + __expf(-x));
}
__device__ __forceinline__ float tanh_fast(float x) {
  x = fminf(fmaxf(x, -15.f), 15.f);
  float e = __expf(-2.f * x);
  return (1.f - e) * __builtin_amdgcn_rcpf(1.f + e);
}

// ---------------- weight fp32 -> fp8 fragment-permute ----------------
__global__ void convert_weights(const float* __restrict__ ewih0, const float* __restrict__ ewhh0,
                                const float* __restrict__ ewih, const float* __restrict__ ewhh,
                                const float* __restrict__ dwih0, const float* __restrict__ dwhh0,
                                const float* __restrict__ dwih, const float* __restrict__ dwhh,
                                const float* __restrict__ lin1w, unsigned char* __restrict__ wb) {
  int i = blockIdx.x * 256 + threadIdx.x;
  if (i >= W_TOTAL) return;
  float v;
  if (i < O_LIN1) {
    const int ph = i / PH_BLOB;
    const int li = i % PH_BLOB;
    const float* wih0 = ph ? dwih0 : ewih0;
    const float* whh0 = ph ? dwhh0 : ewhh0;
    const float* wih  = ph ? dwih  : ewih;
    const float* whh  = ph ? dwhh  : ewhh;
    const int l = li / (6 * SLOT);
    const int r6 = li % (6 * SLOT);
    const int s = r6 / SLOT, r = r6 % SLOT;
    const int w = r >> 11, ks = (r >> 9) & 3, lane = (r >> 3) & 63, e = r & 7;
    const int quad = lane >> 4, ln = lane & 15;
    const int g = (s < 3) ? s : (s - 3);
    const int row = g * 128 + w * 16 + ln;
    const int col = ks * 32 + quad * 8 + e;
    if (s < 3) {  // h-side
      v = (l == 0) ? whh0[row * 128 + col] : whh[(l - 1) * 49152 + row * 128 + col];
    } else {      // x-side (layer 0: wih0 is [384][4], zero-padded beyond col 3)
      v = (l == 0) ? (col < 4 ? wih0[row * 4 + col] : 0.f)
                   : wih[(l - 1) * 49152 + row * 128 + col];
    }
  } else {
    const int r = i - O_LIN1;
    const int w = r >> 11, ks = (r >> 9) & 3, lane = (r >> 3) & 63, e = r & 7;
    const int quad = lane >> 4, ln = lane & 15;
    v = lin1w[(w * 16 + ln) * 128 + ks * 32 + quad * 8 + e];
  }
  wb[i] = (unsigned char)(f2fp8pk(v, v) & 0xFF);
}

__global__ void zero_loss_k(float* out) { out[LOSS_OFF] = 0.f; }

// ---------------- main persistent kernel ----------------
// grid = 256 blocks (M=16 batch rows, 1 block/CU), block = 512 threads (8 waves).
// R4 lesson: 8-wave block => >=2 waves/SIMD => HARD 256-VGPR cap; bf16 weights
// (364 VGPRs) can never be resident. fp8 e4m3 halves fragments to 2 VGPRs each:
// ALL per-phase weights = 87 frags = 174 VGPRs -> fully register-resident, zero
// global loads in the steady-state K-loop. A-side (h, x) is fp8 in swizzled LDS,
// re-quantized each step from the fp32 LDS master hf via v_cvt_pk_fp8_f32.
// Biases live in LDS (register budget). launch_bounds(512,2) = 256-VGPR cap.
__global__ __launch_bounds__(512, 2) void gru_seq2seq(
    const float* __restrict__ inp, const float* __restrict__ tgt,
    const float* __restrict__ enc_bih, const float* __restrict__ enc_bhh,
    const float* __restrict__ dec_bih, const float* __restrict__ dec_bhh,
    const float* __restrict__ lin1_b, const float* __restrict__ lin2_w,
    const float* __restrict__ lin2_b, const unsigned char* __restrict__ wb,
    float* __restrict__ out) {
  const int tid = threadIdx.x;
  const int wave = tid >> 6;
  const int lane = tid & 63;
  const int ln = lane & 15;
  const int quad = lane >> 4;
  const int b0 = blockIdx.x * 16;
  const int j = (wave << 4) + ln;

  __shared__ __align__(16) unsigned char hb8[2][4][16][128];  // fp8 h [parity][l][m][swz k]
  __shared__ __align__(16) unsigned char xt8[2][16][128];     // fp8 x-tile (K=128 padded)
  __shared__ float hf[4][16][128];                            // fp32 h master
  __shared__ float bsum[4][2][128];                           // bih+bhh for r,z
  __shared__ float bnn[4][2][128];                            // bin, bhn
  __shared__ float lin1bs[128];
  __shared__ float lin2ws[4][129];
  __shared__ float lin2bs[4];
  __shared__ float relu_s[16][129];

  for (int i = tid; i < 2 * 4 * 16 * 128; i += 512) ((unsigned char*)hb8)[i] = 0;
  for (int i = tid; i < 2 * 16 * 128; i += 512) ((unsigned char*)xt8)[i] = 0;
  for (int i = tid; i < 4 * 16 * 128; i += 512) ((float*)hf)[i] = 0.f;
  if (tid < 128) lin1bs[tid] = lin1_b[tid];
  { int e = tid >> 7, k = tid & 127; lin2ws[e][k] = lin2_w[e * 128 + k]; }
  if (tid < 4) lin2bs[tid] = lin2_b[tid];

  float loss_local = 0.f;

  // decoder_output[:, 0, :] = inp[:, 0, :]
  if (tid < 64) {
    int m = tid >> 2, e = tid & 3;
    out[DEC_OUT_OFF + (b0 + m) * 400 + e] = inp[(b0 + m) * 256 + e];
  }

  const int fofs = wave * 2048 + lane * 8;  // byte offset [w][ks][lane][8] in a slot

  // lin1 B-frags: register-resident for the whole kernel (8 VGPRs)
  long w1f[4];
#pragma unroll
  for (int ks = 0; ks < 4; ks++)
    w1f[ks] = *(const long*)(wb + O_LIN1 + fofs + ks * 512);

#pragma unroll 1
  for (int ph = 0; ph < 2; ph++) {
    const float* bih = ph ? dec_bih : enc_bih;
    const float* bhh = ph ? dec_bhh : enc_bhh;
    {  // per-phase biases -> LDS (512 threads cover 4*128 exactly)
      int l = tid >> 7, jj = tid & 127;
      bsum[l][0][jj] = bih[l * 384 + jj] + bhh[l * 384 + jj];
      bsum[l][1][jj] = bih[l * 384 + 128 + jj] + bhh[l * 384 + 128 + jj];
      bnn[l][0][jj] = bih[l * 384 + 256 + jj];
      bnn[l][1][jj] = bhh[l * 384 + 256 + jj];
    }
    // step-0 input for both phases: inp[:, 0, :]
    if (tid < 64) {
      int m = tid >> 2, e = tid & 3;
      xt8[0][m][(m << 3) | e] =
          (unsigned char)(f2fp8pk(inp[(b0 + m) * 256 + e], 0.f) & 0xFF);
    }
    __syncthreads();

    // ---- per-phase REGISTER-RESIDENT fp8 weights (174 VGPRs) ----
    const unsigned char* PB = wb + ph * PH_BLOB + fofs;
    long whf[4][3][4];  // h-side [l][gate][ks]
    long wxf[3][3][4];  // x-side [l-1][gate][ks], layers 1..3
    long wx0f[3];       // x-side layer 0, ks=0 only (cols>=4 are zero)
#pragma unroll
    for (int l = 0; l < 4; l++)
#pragma unroll
      for (int g = 0; g < 3; g++)
#pragma unroll
        for (int ks = 0; ks < 4; ks++)
          whf[l][g][ks] = *(const long*)(PB + l * 6 * SLOT + g * SLOT + ks * 512);
#pragma unroll
    for (int l = 1; l < 4; l++)
#pragma unroll
      for (int g = 0; g < 3; g++)
#pragma unroll
        for (int ks = 0; ks < 4; ks++)
          wxf[l - 1][g][ks] =
              *(const long*)(PB + l * 6 * SLOT + (3 + g) * SLOT + ks * 512);
#pragma unroll
    for (int g = 0; g < 3; g++) wx0f[g] = *(const long*)(PB + (3 + g) * SLOT);

    const float l1b = lin1bs[j];
    const int T = ph ? T_DEC : T_ENC;

#pragma unroll 1
    for (int t = 0; t < T; t++) {
      const int p = t & 1;
#pragma unroll
      for (int l = 0; l < 4; l++) {
        f32x4 ar = {0.f, 0.f, 0.f, 0.f}, az = {0.f, 0.f, 0.f, 0.f};
        f32x4 ani = {0.f, 0.f, 0.f, 0.f}, anh = {0.f, 0.f, 0.f, 0.f};
        const unsigned char* ahb = &hb8[1 - p][l][0][0] + ln * 128;
        const unsigned char* axb =
            (l ? &hb8[p][l - 1][0][0] : &xt8[p][0][0]) + ln * 128;
#pragma unroll
        for (int ks = 0; ks < 4; ks++) {
          const int pc = (((ks * 4 + quad) ^ ln) << 3);
          long a_h = *(const long*)(ahb + pc);
          ar = MFMA8(a_h, whf[l][0][ks], ar);
          az = MFMA8(a_h, whf[l][1][ks], az);
          anh = MFMA8(a_h, whf[l][2][ks], anh);
          if (l > 0) {
            long a_x = *(const long*)(axb + pc);
            ar = MFMA8(a_x, wxf[l - 1][0][ks], ar);
            az = MFMA8(a_x, wxf[l - 1][1][ks], az);
            ani = MFMA8(a_x, wxf[l - 1][2][ks], ani);
          }
        }
        if (l == 0) {  // x-side of layer 0: only ks=0 carries data
          const int pc0 = ((quad ^ ln) << 3);
          long a_x0 = *(const long*)(axb + pc0);
          ar = MFMA8(a_x0, wx0f[0], ar);
          az = MFMA8(a_x0, wx0f[1], az);
          ani = MFMA8(a_x0, wx0f[2], ani);
        }
        // ---- epilogue ----
        const float brl = bsum[l][0][j], bzl = bsum[l][1][j];
        const float binl = bnn[l][0][j], bhnl = bnn[l][1][j];
        float hnv[4];
#pragma unroll
        for (int r = 0; r < 4; r++) {
          const int m = quad * 4 + r;
          const float hp = hf[l][m][j];
          const float rg = sigm(ar[r] + brl);
          const float zg = sigm(az[r] + bzl);
          const float ng = tanh_fast(ani[r] + binl + rg * (anh[r] + bhnl));
          const float hn = (1.f - zg) * ng + zg * hp;
          hf[l][m][j] = hn;
          hnv[r] = hn;
          if (!ph) {
            if (l == 3) out[ENC_OUT_OFF + ((b0 + m) * 64 + t) * 128 + j] = hn;
            if (t == T_ENC - 1) out[ENC_HID_OFF + (l * 4096 + b0 + m) * 128 + j] = hn;
          } else if (t == T_DEC - 1) {
            out[DEC_HID_OFF + (l * 4096 + b0 + m) * 128 + j] = hn;
          }
        }
        // fp8 re-quantized h -> swizzled LDS (2 packed cvts, 4 byte stores)
        {
          unsigned pkA = f2fp8pk(hnv[0], hnv[1]);
          unsigned pkB = f2fp8pk(hnv[2], hnv[3]);
          unsigned char* hw = &hb8[p][l][0][0];
          const int m0 = quad * 4;
#pragma unroll
          for (int r = 0; r < 4; r++) {
            const int m = m0 + r;
            const unsigned pk = (r < 2) ? pkA : pkB;
            hw[m * 128 + ((((j >> 3) ^ m) << 3) | (j & 7))] =
                (unsigned char)((pk >> ((r & 1) * 8)) & 0xFF);
          }
        }
        // prefetch next step's x before the barrier (readers come after it)
        if (l == 3 && (t + 1) < T && tid < 64) {
          int m = tid >> 2, e = tid & 3;
          float xv = ph ? tgt[(b0 + m) * 400 + (t + 1) * 4 + e]
                        : inp[(b0 + m) * 256 + (t + 1) * 4 + e];
          xt8[1 - p][m][(m << 3) | e] = (unsigned char)(f2fp8pk(xv, 0.f) & 0xFF);
        }
        __syncthreads();
      }  // layer

      if (ph) {
        // ---- lin1 (128x128) via fp8 MFMA, register-resident weights ----
        f32x4 a1 = {0.f, 0.f, 0.f, 0.f};
        const unsigned char* h3 = &hb8[p][3][0][0] + ln * 128;
#pragma unroll
        for (int ks = 0; ks < 4; ks++) {
          const int pc = (((ks * 4 + quad) ^ ln) << 3);
          long ah = *(const long*)(h3 + pc);
          a1 = MFMA8(ah, w1f[ks], a1);
        }
#pragma unroll
        for (int r = 0; r < 4; r++) {
          const int m = quad * 4 + r;
          const float v = a1[r] + l1b;
          relu_s[m][j] = v > 0.f ? v : 0.f;
        }
        __syncthreads();
        // ---- lin2 (4x128) + loss, threads 0..63 ----
        if (tid < 64) {
          const int m = tid >> 2, e = tid & 3;
          float acc = lin2bs[e];
#pragma unroll 8
          for (int k = 0; k < 128; k++) acc += relu_s[m][k] * lin2ws[e][k];
          const int oidx = (b0 + m) * 400 + (t + 1) * 4 + e;
          out[DEC_OUT_OFF + oidx] = acc;
          const float d = acc - tgt[oidx];
          loss_local += d * d;
        }
      }
    }  // t
  }  // phase

  // ---- loss reduction: only wave 0 has nonzero partials ----
  loss_local *= (1.f / 16384.f);  // mean over (B=4096, E=4)
#pragma unroll
  for (int off = 32; off; off >>= 1) loss_local += __shfl_down(loss_local, off);
  if (tid == 0) atomicAdd(&out[LOSS_OFF], loss_local);
}

// ---------------- launch ----------------
extern "C" void kernel_launch(void* const* d_in, const int* in_sizes, int n_in,
                              void* d_out, int out_size, void* d_ws, size_t ws_size,
                              hipStream_t stream) {
  const float* inp      = (const float*)d_in[0];
  const float* tgt      = (const float*)d_in[1];
  const float* enc_wih0 = (const float*)d_in[2];
  const float* enc_whh0 = (const float*)d_in[3];
  const float* enc_wih  = (const float*)d_in[4];
  const float* enc_whh  = (const float*)d_in[5];
  const float* enc_bih  = (const float*)d_in[6];
  const float* enc_bhh  = (const float*)d_in[7];
  const float* dec_wih0 = (const float*)d_in[8];
  const float* dec_whh0 = (const float*)d_in[9];
  const float* dec_wih  = (const float*)d_in[10];
  const float* dec_whh  = (const float*)d_in[11];
  const float* dec_bih  = (const float*)d_in[12];
  const float* dec_bhh  = (const float*)d_in[13];
  const float* lin1_w   = (const float*)d_in[14];
  const float* lin1_b   = (const float*)d_in[15];
  const float* lin2_w   = (const float*)d_in[16];
  const float* lin2_b   = (const float*)d_in[17];
  unsigned char* wb = (unsigned char*)d_ws;
  float* out = (float*)d_out;

  hipLaunchKernelGGL(convert_weights, dim3((W_TOTAL + 255) / 256), dim3(256), 0, stream,
                     enc_wih0, enc_whh0, enc_wih, enc_whh, dec_wih0, dec_whh0, dec_wih,
                     dec_whh, lin1_w, wb);
  hipLaunchKernelGGL(zero_loss_k, dim3(1), dim3(1), 0, stream, out);
  hipLaunchKernelGGL(gru_seq2seq, dim3(256), dim3(512), 0, stream,
                     inp, tgt, enc_bih, enc_bhh, dec_bih, dec_bhh,
                     lin1_b, lin2_w, lin2_b, wb, out);
}